// Round 1
// baseline (69.856 us; speedup 1.0000x reference)
//
#include <hip/hip_runtime.h>
#include <math.h>

// Problem constants (reference: x [8,2,224,224] f32, weights [1,4] f32)
#define BATCH 8
#define CIN   2
#define H     224
#define W     224
#define NH    223
#define NW    223
#define PIXB  (H * W)          // floats per channel per batch = 50176
#define NPB   (CIN * H * W)    // floats per batch = 100352
#define PER_B (NH * NW)        // output positions per batch = 49729
#define PI_F  3.14159265358979323846f

// Monotonic float<->uint encoding so atomicMin/Max on uint == float min/max
__device__ __forceinline__ unsigned enc_f(float f) {
    unsigned u = __float_as_uint(f);
    return (u & 0x80000000u) ? ~u : (u | 0x80000000u);
}
__device__ __forceinline__ float dec_f(unsigned e) {
    unsigned u = (e & 0x80000000u) ? (e & 0x7FFFFFFFu) : ~e;
    return __uint_as_float(u);
}

// Kernel 1: per-batch global min/max. 32 blocks per batch, 256 threads each.
// ws[b]   (uint) = encoded min  (init 0xFFFFFFFF by memset)
// ws[b+8] (uint) = encoded max  (init 0x00000000 by memset)
__global__ __launch_bounds__(256) void minmax_kernel(
        const float* __restrict__ x, unsigned* __restrict__ ws) {
    const int BPB = 32;                 // blocks per batch
    int b  = blockIdx.x / BPB;
    int cb = blockIdx.x % BPB;
    const float4* xb = (const float4*)(x + (size_t)b * NPB);
    const int n4  = NPB / 4;            // 25088 float4 per batch
    const int per = n4 / BPB;           // 784 float4 per block
    float lmin =  INFINITY, lmax = -INFINITY;
    for (int idx = cb * per + threadIdx.x; idx < (cb + 1) * per; idx += 256) {
        float4 v = xb[idx];
        lmin = fminf(lmin, fminf(fminf(v.x, v.y), fminf(v.z, v.w)));
        lmax = fmaxf(lmax, fmaxf(fmaxf(v.x, v.y), fmaxf(v.z, v.w)));
    }
    // wave64 butterfly-ish reduce via shfl_down
    #pragma unroll
    for (int off = 32; off > 0; off >>= 1) {
        lmin = fminf(lmin, __shfl_down(lmin, off, 64));
        lmax = fmaxf(lmax, __shfl_down(lmax, off, 64));
    }
    __shared__ float smin[4], smax[4];
    int wid = threadIdx.x >> 6;
    if ((threadIdx.x & 63) == 0) { smin[wid] = lmin; smax[wid] = lmax; }
    __syncthreads();
    if (threadIdx.x == 0) {
        #pragma unroll
        for (int i = 1; i < 4; ++i) {
            lmin = fminf(lmin, smin[i]);
            lmax = fmaxf(lmax, smax[i]);
        }
        atomicMin(&ws[b],     enc_f(lmin));
        atomicMax(&ws[b + 8], enc_f(lmax));
    }
}

// Kernel 2: analytic 4-qubit circuit per output position.
// z_q = cos(a_q) cos(b_q) cos(w_q) - sin(a_q) sin(w_q)
// out[b,0] = z1 z2 z3; out[b,1] = z0 z1; out[b,2] = z0 z1 z2; out[b,3] = z0 z1 z2 z3
__global__ __launch_bounds__(256) void quanv_kernel(
        const float* __restrict__ x, const float* __restrict__ wts,
        const unsigned* __restrict__ ws, float* __restrict__ out) {
    int t = blockIdx.x * 256 + threadIdx.x;
    if (t >= BATCH * PER_B) return;
    int b = t / PER_B;
    int r = t - b * PER_B;
    int i = r / NW;
    int j = r - i * NW;

    float gmin  = dec_f(ws[b]);
    float gmax  = dec_f(ws[b + 8]);
    float scale = PI_F / (gmax - gmin + 1e-8f);

    const float* c0 = x + (size_t)b * NPB + (size_t)i * W + j;
    const float* c1 = c0 + PIXB;

    float z[4];
    #pragma unroll
    for (int q = 0; q < 4; ++q) {
        int kh = q >> 1, kw = q & 1;
        float pa = c0[kh * W + kw];     // channel 0 -> RX angle a_q
        float pb = c1[kh * W + kw];     // channel 1 -> RY angle b_q
        float a  = (pa - gmin) * scale;
        float bb = (pb - gmin) * scale;
        float sa, ca;
        __sincosf(a, &sa, &ca);
        float cb = __cosf(bb);
        float sw, cw;
        __sincosf(wts[q], &sw, &cw);
        z[q] = ca * cb * cw - sa * sw;
    }

    size_t base = (size_t)b * 4 * PER_B + r;
    float z01 = z[0] * z[1];
    out[base]             = z[1] * z[2] * z[3];
    out[base + PER_B]     = z01;
    out[base + 2 * PER_B] = z01 * z[2];
    out[base + 3 * PER_B] = z01 * z[2] * z[3];
}

extern "C" void kernel_launch(void* const* d_in, const int* in_sizes, int n_in,
                              void* d_out, int out_size, void* d_ws, size_t ws_size,
                              hipStream_t stream) {
    const float* x   = (const float*)d_in[0];   // [8,2,224,224] f32
    const float* wts = (const float*)d_in[1];   // [1,4] f32
    float* out = (float*)d_out;                 // [8,4,223,223] f32
    unsigned* ws = (unsigned*)d_ws;

    // init encoded min slots to 0xFFFFFFFF (== +inf side), max slots to 0x0
    hipMemsetAsync(ws, 0xFF, BATCH * sizeof(unsigned), stream);
    hipMemsetAsync(ws + BATCH, 0x00, BATCH * sizeof(unsigned), stream);

    minmax_kernel<<<BATCH * 32, 256, 0, stream>>>(x, ws);

    int total = BATCH * PER_B;                  // 397832
    int blocks = (total + 255) / 256;           // 1555
    quanv_kernel<<<blocks, 256, 0, stream>>>(x, wts, ws, out);
}

// Round 2
// 61.211 us; speedup vs baseline: 1.1412x; 1.1412x over previous
//
#include <hip/hip_runtime.h>
#include <math.h>

// Problem constants (reference: x [8,2,224,224] f32, weights [1,4] f32)
#define BATCH 8
#define CIN   2
#define H     224
#define W     224
#define NH    223
#define NW    223
#define PIXB  (H * W)          // floats per channel per batch = 50176
#define NPB   (CIN * H * W)    // floats per batch = 100352
#define PER_B (NH * NW)        // output positions per batch = 49729
#define NBPB  ((PER_B + 255) / 256)   // blocks per batch in quanv = 195
#define BPB   32               // reduction blocks per batch
#define PI_F  3.14159265358979323846f

// Kernel 1: per-block partial min/max. 32 blocks per batch, 256 threads each.
// No atomics, no init: ws[b*32+cb] = block min, ws[256 + b*32+cb] = block max.
__global__ __launch_bounds__(256) void minmax_kernel(
        const float* __restrict__ x, float* __restrict__ ws) {
    int b  = blockIdx.x / BPB;
    int cb = blockIdx.x % BPB;
    const float4* xb = (const float4*)(x + (size_t)b * NPB);
    const int n4  = NPB / 4;            // 25088 float4 per batch
    const int per = n4 / BPB;           // 784 float4 per block
    float lmin =  INFINITY, lmax = -INFINITY;
    for (int idx = cb * per + threadIdx.x; idx < (cb + 1) * per; idx += 256) {
        float4 v = xb[idx];
        lmin = fminf(lmin, fminf(fminf(v.x, v.y), fminf(v.z, v.w)));
        lmax = fmaxf(lmax, fmaxf(fmaxf(v.x, v.y), fmaxf(v.z, v.w)));
    }
    #pragma unroll
    for (int off = 32; off > 0; off >>= 1) {
        lmin = fminf(lmin, __shfl_down(lmin, off, 64));
        lmax = fmaxf(lmax, __shfl_down(lmax, off, 64));
    }
    __shared__ float smin[4], smax[4];
    int wid = threadIdx.x >> 6;
    if ((threadIdx.x & 63) == 0) { smin[wid] = lmin; smax[wid] = lmax; }
    __syncthreads();
    if (threadIdx.x == 0) {
        #pragma unroll
        for (int i = 1; i < 4; ++i) {
            lmin = fminf(lmin, smin[i]);
            lmax = fmaxf(lmax, smax[i]);
        }
        ws[b * BPB + cb]               = lmin;
        ws[256 + b * BPB + cb]         = lmax;
    }
}

// Kernel 2: analytic 4-qubit circuit per output position.
// z_q = cos(a_q) cos(b_q) cos(w_q) - sin(a_q) sin(w_q)
// out[b,0] = z1 z2 z3; out[b,1] = z0 z1; out[b,2] = z0 z1 z2; out[b,3] = z0 z1 z2 z3
// Grid: (NBPB, BATCH). b = blockIdx.y (block-uniform). First 32 lanes reduce
// the 32 partials for this batch, broadcast via LDS.
__global__ __launch_bounds__(256) void quanv_kernel(
        const float* __restrict__ x, const float* __restrict__ wts,
        const float* __restrict__ ws, float* __restrict__ out) {
    int b = blockIdx.y;
    __shared__ float sred[2];
    if (threadIdx.x < 32) {
        float mn = ws[b * BPB + threadIdx.x];
        float mx = ws[256 + b * BPB + threadIdx.x];
        #pragma unroll
        for (int off = 16; off > 0; off >>= 1) {
            mn = fminf(mn, __shfl_xor(mn, off, 32));
            mx = fmaxf(mx, __shfl_xor(mx, off, 32));
        }
        if (threadIdx.x == 0) { sred[0] = mn; sred[1] = mx; }
    }
    __syncthreads();
    float gmin  = sred[0];
    float scale = PI_F / (sred[1] - gmin + 1e-8f);

    int r = blockIdx.x * 256 + threadIdx.x;
    if (r >= PER_B) return;
    int i = r / NW;
    int j = r - i * NW;

    const float* c0 = x + (size_t)b * NPB + (size_t)i * W + j;
    const float* c1 = c0 + PIXB;

    float z[4];
    #pragma unroll
    for (int q = 0; q < 4; ++q) {
        int kh = q >> 1, kw = q & 1;
        float pa = c0[kh * W + kw];     // channel 0 -> RX angle a_q
        float pb = c1[kh * W + kw];     // channel 1 -> RY angle b_q
        float a  = (pa - gmin) * scale;
        float bb = (pb - gmin) * scale;
        float sa, ca;
        __sincosf(a, &sa, &ca);
        float cb = __cosf(bb);
        float sw, cw;
        __sincosf(wts[q], &sw, &cw);
        z[q] = ca * cb * cw - sa * sw;
    }

    size_t base = (size_t)b * 4 * PER_B + r;
    float z01 = z[0] * z[1];
    out[base]             = z[1] * z[2] * z[3];
    out[base + PER_B]     = z01;
    out[base + 2 * PER_B] = z01 * z[2];
    out[base + 3 * PER_B] = z01 * z[2] * z[3];
}

extern "C" void kernel_launch(void* const* d_in, const int* in_sizes, int n_in,
                              void* d_out, int out_size, void* d_ws, size_t ws_size,
                              hipStream_t stream) {
    const float* x   = (const float*)d_in[0];   // [8,2,224,224] f32
    const float* wts = (const float*)d_in[1];   // [1,4] f32
    float* out = (float*)d_out;                 // [8,4,223,223] f32
    float* ws  = (float*)d_ws;

    minmax_kernel<<<BATCH * BPB, 256, 0, stream>>>(x, ws);
    quanv_kernel<<<dim3(NBPB, BATCH), 256, 0, stream>>>(x, wts, ws, out);
}